// Round 4
// baseline (578.842 us; speedup 1.0000x reference)
//
#include <hip/hip_runtime.h>
#include <math.h>

// Problem constants
#define HID   4096
#define SLOTS 8
#define HEADS 8
#define BD    512
#define HD    64
#define BB    4
#define SS    4096
#define R64   64          // HEADS*SLOTS rows; r = h*8 + n
#define LSTR  72          // padded LDS row stride (bf16 elems) for register-staged tiles
#define KC    1024        // K-chunk per block (K-split)
#define NKZ   4           // number of K chunks
#define NT    16          // K-steps per chunk (KC/64)

typedef __attribute__((ext_vector_type(8))) short bf16x8;
typedef __attribute__((ext_vector_type(4))) float f32x4;

// fp32 -> bf16 bits, round-to-nearest-even (inputs finite)
__device__ __forceinline__ unsigned short f2bf(float x) {
  unsigned int u = __builtin_bit_cast(unsigned int, x);
  return (unsigned short)((u + 0x7fffu + ((u >> 16) & 1u)) >> 16);
}

// async global->LDS, 16 bytes per lane (literal size per guide)
__device__ __forceinline__ void gl16(const void* g, void* l) {
  __builtin_amdgcn_global_load_lds(
      (const __attribute__((address_space(1))) unsigned int*)g,
      (__attribute__((address_space(3))) unsigned int*)l, 16, 0, 0);
}

// ---- 1: Q = ms @ Wq^T  (8x512). One wave per output element.
__global__ void q_kernel(const float* __restrict__ ms, const float* __restrict__ Wq,
                         float* __restrict__ Q) {
  int w = (blockIdx.x * blockDim.x + threadIdx.x) >> 6;
  int lane = threadIdx.x & 63;
  if (w >= SLOTS * BD) return;
  int n = w >> 9, o = w & (BD - 1);
  const float* a = ms + n * HID;
  const float* b = Wq + (size_t)o * HID;
  float acc = 0.f;
  for (int i = lane; i < HID; i += 64) acc = fmaf(a[i], b[i], acc);
  #pragma unroll
  for (int off = 32; off; off >>= 1) acc += __shfl_down(acc, off, 64);
  if (lane == 0) Q[w] = acc;
}

// ---- 2: QW[r][i] = 0.125 * sum_d Q[n][h*64+d] * Wk[h*64+d][i],  r = h*8+n  (bf16 out)
__global__ void qw_kernel(const float* __restrict__ Q, const float* __restrict__ Wk,
                          unsigned short* __restrict__ QW) {
  int idx = blockIdx.x * blockDim.x + threadIdx.x;   // 64*4096
  int r = idx >> 12, i = idx & (HID - 1);
  int h = r >> 3, n = r & 7;
  const float* q  = Q + n * BD + h * HD;
  const float* wk = Wk + (size_t)(h * HD) * HID + i;
  float acc = 0.f;
  #pragma unroll 8
  for (int d = 0; d < HD; ++d) acc = fmaf(q[d], wk[(size_t)d * HID], acc);
  QW[idx] = f2bf(acc * 0.125f);
}

// ---- 3: partial scores sp[kz][b][r][s] = sum_{k chunk} hs[b][s][k]*QW[r][k]  (bf16 MFMA)
// FUSED hs->bf16 conversion: reads fp32 hs, converts in-register, ds_writes the
// swizzled A tile AND stores the bf16 tile to hsb (side product for ctx_mfma).
// grid (64 s-tiles, 4 b, 4 kz), 256 thr. M=64(s) x N=64(r), K=1024.
// LDS layout: lds_byte(row,kb) = row*128 + (kb ^ ((row&7)<<4)).
__global__ __launch_bounds__(256) void scores_mfma(const float* __restrict__ hs,
                                                   const unsigned short* __restrict__ QW,
                                                   unsigned short* __restrict__ hsb,
                                                   float* __restrict__ sp) {
  __shared__ __align__(16) unsigned short As[2][4096];  // [s(64)][k(64)] swizzled
  __shared__ __align__(16) unsigned short Bs[2][4096];  // [r(64)][k(64)] swizzled
  const int stile = blockIdx.x, b = blockIdx.y, kz = blockIdx.z;
  const int tid = threadIdx.x;
  const int wv = tid >> 6, lane = tid & 63;
  const int quad = lane >> 4, l16 = lane & 15;
  // A staging (reg->LDS): row 0..63, 16 contiguous fp32 at elem (tid&3)*16
  const int arow = tid >> 2, acol = (tid & 3) << 4;
  const float* aSrc = hs + ((size_t)(b * SS + stile * 64 + arow)) * HID + kz * KC + acol;
  unsigned short* hOut = hsb + ((size_t)(b * SS + stile * 64 + arow)) * HID + kz * KC + acol;
  const int aswz = (arow & 7) << 4;
  const int abyte0 = arow * 128 + ((acol * 2) ^ aswz);
  const int abyte1 = arow * 128 + ((acol * 2 + 16) ^ aswz);
  // B staging via global_load_lds (linear LDS dest), source pre-swizzled
  const int trow = tid >> 3;                 // 0..31
  const int tslot = (tid & 7) << 4;          // byte slot 0..112
  const int scol = tslot ^ ((trow & 7) << 4);
  const char* bSrc0 = (const char*)QW + (((size_t)trow) * HID + kz * KC) * 2 + scol;
  const char* bSrc1 = (const char*)QW + (((size_t)(32 + trow)) * HID + kz * KC) * 2 + scol;

  f32x4 acc[4] = {};
  // prologue: step 0 regs
  float4 f0 = *(const float4*)(aSrc);
  float4 f1 = *(const float4*)(aSrc + 4);
  float4 f2 = *(const float4*)(aSrc + 8);
  float4 f3 = *(const float4*)(aSrc + 12);
  gl16(bSrc0, &Bs[0][tid * 8]);
  gl16(bSrc1, &Bs[0][2048 + tid * 8]);
  {
    union { unsigned short us[16]; uint4 q[2]; } u;
    float f[16] = {f0.x, f0.y, f0.z, f0.w, f1.x, f1.y, f1.z, f1.w,
                   f2.x, f2.y, f2.z, f2.w, f3.x, f3.y, f3.z, f3.w};
    #pragma unroll
    for (int j = 0; j < 16; ++j) u.us[j] = f2bf(f[j]);
    *(uint4*)((char*)&As[0][0] + abyte0) = u.q[0];
    *(uint4*)((char*)&As[0][0] + abyte1) = u.q[1];
    *(uint4*)(hOut)     = u.q[0];
    *(uint4*)(hOut + 8) = u.q[1];
  }
  // step 1 regs
  f0 = *(const float4*)(aSrc + 64);
  f1 = *(const float4*)(aSrc + 68);
  f2 = *(const float4*)(aSrc + 72);
  f3 = *(const float4*)(aSrc + 76);
  __syncthreads();

  const int sw = (l16 & 7) << 4;
  for (int c = 0; c < NT; ++c) {
    const int cur = c & 1, nxt = cur ^ 1;
    if (c < NT - 1) {
      const size_t boff = (size_t)(c + 1) * 128;
      gl16(bSrc0 + boff, &Bs[nxt][tid * 8]);
      gl16(bSrc1 + boff, &Bs[nxt][2048 + tid * 8]);
      union { unsigned short us[16]; uint4 q[2]; } u;
      float f[16] = {f0.x, f0.y, f0.z, f0.w, f1.x, f1.y, f1.z, f1.w,
                     f2.x, f2.y, f2.z, f2.w, f3.x, f3.y, f3.z, f3.w};
      #pragma unroll
      for (int j = 0; j < 16; ++j) u.us[j] = f2bf(f[j]);
      *(uint4*)((char*)&As[nxt][0] + abyte0) = u.q[0];
      *(uint4*)((char*)&As[nxt][0] + abyte1) = u.q[1];
      unsigned short* ho = hOut + (size_t)(c + 1) * 64;
      *(uint4*)(ho)     = u.q[0];
      *(uint4*)(ho + 8) = u.q[1];
      if (c < NT - 2) {
        const float* an = aSrc + (size_t)(c + 2) * 64;
        f0 = *(const float4*)(an);
        f1 = *(const float4*)(an + 4);
        f2 = *(const float4*)(an + 8);
        f3 = *(const float4*)(an + 12);
      }
    }
    const char* ab = (const char*)&As[cur][0];
    const char* bb = (const char*)&Bs[cur][0];
    #pragma unroll
    for (int ks = 0; ks < 2; ++ks) {
      bf16x8 bfrag = *(const bf16x8*)(bb + (wv * 16 + l16) * 128 + ((ks * 64 + quad * 16) ^ sw));
      #pragma unroll
      for (int mt = 0; mt < 4; ++mt) {
        bf16x8 afrag = *(const bf16x8*)(ab + (mt * 16 + l16) * 128 + ((ks * 64 + quad * 16) ^ sw));
        acc[mt] = __builtin_amdgcn_mfma_f32_16x16x32_bf16(afrag, bfrag, acc[mt], 0, 0, 0);
      }
    }
    __syncthreads();
  }
  const int r = wv * 16 + l16;
  #pragma unroll
  for (int mt = 0; mt < 4; ++mt) {
    int s = stile * 64 + mt * 16 + quad * 4;
    float4 v = make_float4(acc[mt][0], acc[mt][1], acc[mt][2], acc[mt][3]);
    *(float4*)(sp + ((size_t)((kz * BB + b) * R64 + r)) * SS + s) = v;
  }
}

// ---- 4: softmax over s per (b,r); sums the 4 K-partials, mask applied; bf16 attn out.
__global__ __launch_bounds__(256) void softmax_kernel(const float* __restrict__ sp,
                                                      const int* __restrict__ mask,
                                                      unsigned short* __restrict__ attn) {
  int br = blockIdx.x;            // b*64 + r
  int b = br >> 6;
  int tid = threadIdx.x;
  const float* p0 = sp + ((size_t)(0 * BB * R64) + br) * SS;
  const float* p1 = sp + ((size_t)(1 * BB * R64) + br) * SS;
  const float* p2 = sp + ((size_t)(2 * BB * R64) + br) * SS;
  const float* p3 = sp + ((size_t)(3 * BB * R64) + br) * SS;
  const int* mrow = mask + b * SS;
  float vals[16];
  float mx = -INFINITY;
  #pragma unroll
  for (int j = 0; j < 16; ++j) {
    int s = tid + j * 256;
    float v = p0[s] + p1[s] + p2[s] + p3[s];
    if (mrow[s] == 0) v = -INFINITY;
    vals[j] = v;
    mx = fmaxf(mx, v);
  }
  __shared__ float redm[4], reds[4];
  #pragma unroll
  for (int off = 32; off; off >>= 1) mx = fmaxf(mx, __shfl_down(mx, off, 64));
  if ((tid & 63) == 0) redm[tid >> 6] = mx;
  __syncthreads();
  mx = fmaxf(fmaxf(redm[0], redm[1]), fmaxf(redm[2], redm[3]));
  float sum = 0.f;
  #pragma unroll
  for (int j = 0; j < 16; ++j) { vals[j] = expf(vals[j] - mx); sum += vals[j]; }
  #pragma unroll
  for (int off = 32; off; off >>= 1) sum += __shfl_down(sum, off, 64);
  if ((tid & 63) == 0) reds[tid >> 6] = sum;
  __syncthreads();
  sum = reds[0] + reds[1] + reds[2] + reds[3];
  float inv = 1.f / sum;
  #pragma unroll
  for (int j = 0; j < 16; ++j)
    attn[(size_t)br * SS + tid + j * 256] = f2bf(vals[j] * inv);
}

// ---- 5: partial ctx[kz][b][r][i] = sum_{s chunk} attn[b][r][s]*hsb[b][s][i]  (bf16 MFMA)
// grid (64 i-tiles, 4 b, 4 kz). M=64(r) x N=64(i), K=1024(s).
__global__ __launch_bounds__(256) void ctx_mfma(const unsigned short* __restrict__ attn,
                                                const unsigned short* __restrict__ hsb,
                                                float* __restrict__ ctxp) {
  __shared__ __align__(16) unsigned short As[2][4096];      // [r(64)][s(64)] swizzled
  __shared__ __align__(16) unsigned short Bs[2][64 * LSTR]; // [i(64)][s(64)] padded
  const int itile = blockIdx.x, b = blockIdx.y, kz = blockIdx.z;
  const int tid = threadIdx.x;
  const int wv = tid >> 6, lane = tid & 63;
  const int quad = lane >> 4, l16 = lane & 15;
  // A staging (global_load_lds)
  const int trow = tid >> 3;
  const int tslot = (tid & 7) << 4;
  const int scol = tslot ^ ((trow & 7) << 4);
  const char* aSrc0 = (const char*)attn +
      (((size_t)(b * R64 + trow)) * SS + kz * KC) * 2 + scol;
  const char* aSrc1 = (const char*)attn +
      (((size_t)(b * R64 + 32 + trow)) * SS + kz * KC) * 2 + scol;
  // B staging: thread -> s-pair p (rows 2p,2p+1), i-group g (8 cols)
  const int p = tid & 31, g = tid >> 5;
  const unsigned short* hb = hsb + ((size_t)(b * SS + kz * KC + 2 * p)) * HID + itile * 64 + g * 8;

  f32x4 acc[4] = {};
  // prologue: step 0 into buf 0
  uint4 h0 = *(const uint4*)(hb);
  uint4 h1 = *(const uint4*)(hb + HID);
  gl16(aSrc0, &As[0][tid * 8]);
  gl16(aSrc1, &As[0][2048 + tid * 8]);
  {
    const unsigned short* u0 = (const unsigned short*)&h0;
    const unsigned short* u1 = (const unsigned short*)&h1;
    unsigned int* bs32 = (unsigned int*)&Bs[0][0];
    #pragma unroll
    for (int j = 0; j < 8; ++j)
      bs32[(g * 8 + j) * (LSTR / 2) + p] = (unsigned int)u0[j] | ((unsigned int)u1[j] << 16);
  }
  h0 = *(const uint4*)(hb + (size_t)64 * HID);
  h1 = *(const uint4*)(hb + (size_t)65 * HID);
  __syncthreads();

  const int sw = (l16 & 7) << 4;
  for (int c = 0; c < NT; ++c) {
    const int cur = c & 1, nxt = cur ^ 1;
    if (c < NT - 1) {
      const size_t off = (size_t)(c + 1) * 128;
      gl16(aSrc0 + off, &As[nxt][tid * 8]);
      gl16(aSrc1 + off, &As[nxt][2048 + tid * 8]);
      const unsigned short* u0 = (const unsigned short*)&h0;
      const unsigned short* u1 = (const unsigned short*)&h1;
      unsigned int* bs32 = (unsigned int*)&Bs[nxt][0];
      #pragma unroll
      for (int j = 0; j < 8; ++j)
        bs32[(g * 8 + j) * (LSTR / 2) + p] = (unsigned int)u0[j] | ((unsigned int)u1[j] << 16);
      if (c < NT - 2) {
        const unsigned short* hn = hb + (size_t)(c + 2) * 64 * HID;
        h0 = *(const uint4*)(hn);
        h1 = *(const uint4*)(hn + HID);
      }
    }
    const char* ab = (const char*)&As[cur][0];
    #pragma unroll
    for (int ks = 0; ks < 2; ++ks) {
      bf16x8 bfrag = *(const bf16x8*)&Bs[cur][(wv * 16 + l16) * LSTR + ks * 32 + quad * 8];
      #pragma unroll
      for (int mt = 0; mt < 4; ++mt) {
        bf16x8 afrag = *(const bf16x8*)(ab + (mt * 16 + l16) * 128 + ((ks * 64 + quad * 16) ^ sw));
        acc[mt] = __builtin_amdgcn_mfma_f32_16x16x32_bf16(afrag, bfrag, acc[mt], 0, 0, 0);
      }
    }
    __syncthreads();
  }
  const int i = itile * 64 + wv * 16 + l16;
  #pragma unroll
  for (int mt = 0; mt < 4; ++mt) {
    int r0 = mt * 16 + quad * 4;
    #pragma unroll
    for (int j = 0; j < 4; ++j)
      ctxp[((size_t)((kz * BB + b) * R64 + r0 + j)) * HID + i] = acc[mt][j];
  }
}

// ---- 6: out[b][n][hd] = sum_i (sum_kz ctxp[kz][b][h*8+n][i]) * Wv[hd][i]
// One wave per (b,hd); folds the 4 K-partials inline (L2-resident); Wv streamed once.
__global__ void out_kernel(const float* __restrict__ ctxp, const float* __restrict__ Wv,
                           float* __restrict__ out) {
  int w = (blockIdx.x * blockDim.x + threadIdx.x) >> 6;   // 2048 = BB*BD waves
  int lane = threadIdx.x & 63;
  if (w >= BB * BD) return;
  int b = w >> 9, hd = w & 511, h = hd >> 6;
  const size_t PSTR = (size_t)BB * R64 * HID;
  const float* wvp = Wv + (size_t)hd * HID;
  const float* cb  = ctxp + ((size_t)b * R64 + h * 8) * HID;  // kz=0, 8 consecutive rows
  float acc[8] = {};
  for (int i = lane; i < HID; i += 64) {
    float wv = wvp[i];
    #pragma unroll
    for (int n = 0; n < 8; ++n) {
      size_t o = (size_t)n * HID + i;
      float v = cb[o] + cb[PSTR + o] + cb[2 * PSTR + o] + cb[3 * PSTR + o];
      acc[n] = fmaf(v, wv, acc[n]);
    }
  }
  #pragma unroll
  for (int n = 0; n < 8; ++n) {
    float a = acc[n];
    #pragma unroll
    for (int off = 32; off; off >>= 1) a += __shfl_down(a, off, 64);
    if (lane == 0) out[((size_t)(b * SLOTS + n)) * BD + hd] = a;
  }
}

// ---- 7: y[bn][o] = sum_d out[bn][d] * Wo[o][d]
__global__ void final_kernel(const float* __restrict__ out, const float* __restrict__ Wo,
                             float* __restrict__ y) {
  int w = (blockIdx.x * blockDim.x + threadIdx.x) >> 6;   // 4096 = HID waves
  int lane = threadIdx.x & 63;
  if (w >= HID) return;
  const float* wo = Wo + (size_t)w * BD;
  float wreg[8];
  #pragma unroll
  for (int j = 0; j < 8; ++j) wreg[j] = wo[lane + j * 64];
  for (int bn = 0; bn < BB * SLOTS; ++bn) {
    const float* orow = out + bn * BD;
    float acc = 0.f;
    #pragma unroll
    for (int j = 0; j < 8; ++j) acc = fmaf(orow[lane + j * 64], wreg[j], acc);
    #pragma unroll
    for (int off = 32; off; off >>= 1) acc += __shfl_down(acc, off, 64);
    if (lane == 0) y[(size_t)bn * HID + w] = acc;
  }
}

extern "C" void kernel_launch(void* const* d_in, const int* in_sizes, int n_in,
                              void* d_out, int out_size, void* d_ws, size_t ws_size,
                              hipStream_t stream) {
  const float* hs   = (const float*)d_in[0];
  const int*   mask = (const int*)d_in[1];
  const float* ms   = (const float*)d_in[2];
  const float* Wq   = (const float*)d_in[3];
  const float* Wk   = (const float*)d_in[4];
  const float* Wv   = (const float*)d_in[5];
  const float* Wo   = (const float*)d_in[6];

  // Workspace layout (~163 MB)
  char* ws = (char*)d_ws;
  float*          Q    = (float*)ws;          ws += 4096 * 4;                          // 16 KB
  unsigned short* QW   = (unsigned short*)ws; ws += R64 * HID * 2;                     // 512 KB
  unsigned short* hsb  = (unsigned short*)ws; ws += (size_t)BB * SS * HID * 2;         // 128 MB
  float*          sp   = (float*)ws;          ws += (size_t)NKZ * BB * R64 * SS * 4;   // 16 MB
  unsigned short* attn = (unsigned short*)ws; ws += (size_t)BB * R64 * SS * 2;         // 2 MB
  float*          ctxp = (float*)ws;          ws += (size_t)NKZ * BB * R64 * HID * 4;  // 16 MB
  float*          out  = (float*)ws;                                                   // 64 KB

  q_kernel<<<dim3((SLOTS * BD * 64) / 256), 256, 0, stream>>>(ms, Wq, Q);
  qw_kernel<<<dim3((R64 * HID) / 256), 256, 0, stream>>>(Q, Wk, QW);
  scores_mfma<<<dim3(64, 4, 4), 256, 0, stream>>>(hs, QW, hsb, sp);
  softmax_kernel<<<dim3(BB * R64), 256, 0, stream>>>(sp, mask, attn);
  ctx_mfma<<<dim3(64, 4, 4), 256, 0, stream>>>(attn, hsb, ctxp);
  out_kernel<<<dim3((BB * BD * 64) / 256), 256, 0, stream>>>(ctxp, Wv, out);
  final_kernel<<<dim3((HID * 64) / 256), 256, 0, stream>>>(out, Wo, (float*)d_out);
}